// Round 3
// baseline (304.342 us; speedup 1.0000x reference)
//
#include <hip/hip_runtime.h>

// ---------------- constants from the reference ----------------
constexpr int   T       = 20;
constexpr int   N_LHB   = 2097152;
constexpr int   N_MHB   = 1048576;
constexpr float V_PEAK  = 30.0f;
constexpr float I_TONIC = -1.0f;
constexpr float THRESH  = 0.4f;
constexpr float DECAY   = 0.998f;
constexpr float GAIN    = 0.05f;

constexpr int BLK  = 256;
constexpr int NB_L = N_LHB / (4 * BLK);   // 2048 blocks (float4 per thread)
constexpr int NB_M = N_MHB / (4 * BLK);   // 1024 blocks
constexpr int NBLK = NB_L + NB_M;         // 3072
constexpr int PF   = 4;                   // noise prefetch depth (steps)

// One Izhikevich step; returns spike as 0/1.
// c = drive + I_TONIC + 140 folded;  v1 = v*(0.04v+6) + (c + 0.5n - u)
__device__ __forceinline__ float istep(float& v, float& u, float n, float c) {
    float q  = fmaf(0.5f, n, c) - u;
    float p  = fmaf(0.04f, v, 6.0f);
    float v1 = fmaf(v, p, q);
    float u1 = fmaf(0.98f, u, 0.004f * v);   // u + 0.02*(0.2v - u)
    bool  s  = (v1 >= V_PEAK);
    v = s ? -65.0f : v1;
    u = s ? (u1 + 8.0f) : u1;
    return s ? 1.0f : 0.0f;
}

// Single fused kernel: Izhikevich run for both populations + last-block finalize.
__global__ __launch_bounds__(BLK) void izh_all(
    const float* __restrict__ reward, const float* __restrict__ expected,
    const float* __restrict__ aversion, const float* __restrict__ da,
    const int* __restrict__ goal, const float* __restrict__ frustration,
    const float* __restrict__ v_l, const float* __restrict__ u_l, const float* __restrict__ r_l,
    const float* __restrict__ v_m, const float* __restrict__ u_m, const float* __restrict__ r_m,
    const float* __restrict__ noise_l, const float* __restrict__ noise_m,
    float* __restrict__ partial, unsigned int* __restrict__ counter,
    float* __restrict__ out)
{
    const int bid = blockIdx.x;
    const int tid = threadIdx.x;

    const float4 *v4, *u4, *r4, *np;
    int n4, i;
    float drive;
    if (bid < NB_L) {
        n4 = N_LHB / 4;
        i  = bid * BLK + tid;
        v4 = (const float4*)v_l; u4 = (const float4*)u_l; r4 = (const float4*)r_l;
        np = (const float4*)noise_l;
        drive = fmaxf(0.0f, expected[0] - reward[0]) * 20.0f;   // disappoint*20
    } else {
        n4 = N_MHB / 4;
        i  = (bid - NB_L) * BLK + tid;
        v4 = (const float4*)v_m; u4 = (const float4*)u_m; r4 = (const float4*)r_m;
        np = (const float4*)noise_m;
        drive = aversion[0] * 15.0f;
    }
    const float c = drive + I_TONIC + 140.0f;

    float4 v = v4[i], u = u4[i], r = r4[i];
    // per-thread running rate-sum via EMA linearity: S' = 0.9*S + 0.1*spikecount
    float S = (r.x + r.y) + (r.z + r.w);

    const float4* npp = np + i;
    float4 nb[PF];
    #pragma unroll
    for (int t = 0; t < PF; ++t) nb[t] = npp[(size_t)t * n4];

    #pragma unroll
    for (int t = 0; t < T; ++t) {
        const float4 cn = nb[t % PF];
        if (t + PF < T) nb[t % PF] = npp[(size_t)(t + PF) * n4];
        float cnt = istep(v.x, u.x, cn.x, c) + istep(v.y, u.y, cn.y, c)
                  + istep(v.z, u.z, cn.z, c) + istep(v.w, u.w, cn.w, c);
        S = fmaf(0.1f, cnt, 0.9f * S);
    }

    // deterministic block reduction
    #pragma unroll
    for (int o = 32; o > 0; o >>= 1) S += __shfl_down(S, o, 64);
    __shared__ float sh[4];
    if ((tid & 63) == 0) sh[tid >> 6] = S;
    __syncthreads();

    __shared__ unsigned int amLast;
    if (tid == 0) {
        float ps = (sh[0] + sh[1]) + (sh[2] + sh[3]);
        __hip_atomic_store(&partial[bid], ps, __ATOMIC_RELEASE, __HIP_MEMORY_SCOPE_AGENT);
        unsigned int old = __hip_atomic_fetch_add(counter, 1u, __ATOMIC_ACQ_REL,
                                                  __HIP_MEMORY_SCOPE_AGENT);
        amLast = (old == (unsigned)(NBLK - 1)) ? 1u : 0u;
    }
    __syncthreads();
    if (amLast == 0u) return;

    // ---------- last arriving block: final reduction + scalar bookkeeping ----------
    float sl = 0.0f, sm = 0.0f;
    for (int k = tid; k < NB_L; k += BLK)
        sl += __hip_atomic_load(&partial[k], __ATOMIC_RELAXED, __HIP_MEMORY_SCOPE_AGENT);
    for (int k = tid; k < NB_M; k += BLK)
        sm += __hip_atomic_load(&partial[NB_L + k], __ATOMIC_RELAXED, __HIP_MEMORY_SCOPE_AGENT);
    #pragma unroll
    for (int o = 32; o > 0; o >>= 1) {
        sl += __shfl_down(sl, o, 64);
        sm += __shfl_down(sm, o, 64);
    }
    __shared__ float sh2[8];
    if ((tid & 63) == 0) { sh2[tid >> 6] = sl; sh2[4 + (tid >> 6)] = sm; }
    __syncthreads();

    if (tid == 0) {
        float lhb_mean = ((sh2[0] + sh2[1]) + (sh2[2] + sh2[3])) / (float)N_LHB;
        float mhb_mean = ((sh2[4] + sh2[5]) + (sh2[6] + sh2[7])) / (float)N_MHB;

        float rpe = reward[0] - expected[0];
        float disappoint = fmaxf(0.0f, -rpe);
        float da_supp = fminf(0.5f, lhb_mean * 5.0f);
        float ht5_supp = fminf(0.3f, lhb_mean * 3.0f);

        int g = goal[0];
        float f[4];
        #pragma unroll
        for (int k = 0; k < 4; ++k) f[k] = frustration[k] * DECAY;
        f[g] += (rpe < -0.05f) ? GAIN * fabsf(rpe) : 0.0f;
        f[g] *= (rpe > 0.1f) ? 0.8f : 1.0f;
        #pragma unroll
        for (int k = 0; k < 4; ++k) f[k] = fminf(1.0f, fmaxf(0.0f, f[k]));
        float helplessness = fmaxf(fmaxf(f[0], f[1]), fmaxf(f[2], f[3]));
        float sw = (f[g] > THRESH) ? 1.0f : 0.0f;
        f[g] *= (sw > 0.0f) ? 0.3f : 1.0f;

        float dopa_mod = fmaxf(0.5f, 2.0f * (1.0f - da[0]));
        float explore = fminf(1.0f, disappoint * 2.0f + lhb_mean * 3.0f);

        out[0] = disappoint;
        out[1] = da_supp;
        out[2] = ht5_supp;
        out[3] = lhb_mean;
        out[4] = mhb_mean;
        out[5] = explore;
        out[6] = helplessness;
        out[7] = sw;
        #pragma unroll
        for (int k = 0; k < 4; ++k) out[8 + k]  = f[k] * 0.5f * dopa_mod;
        #pragma unroll
        for (int k = 0; k < 4; ++k) out[12 + k] = f[k];
    }
}

extern "C" void kernel_launch(void* const* d_in, const int* in_sizes, int n_in,
                              void* d_out, int out_size, void* d_ws, size_t ws_size,
                              hipStream_t stream) {
    const float* reward      = (const float*)d_in[0];
    const float* expected    = (const float*)d_in[1];
    const float* aversion    = (const float*)d_in[2];
    const float* da          = (const float*)d_in[3];
    const int*   goal        = (const int*)d_in[4];
    const float* frustration = (const float*)d_in[5];
    const float* v_l         = (const float*)d_in[6];
    const float* u_l         = (const float*)d_in[7];
    const float* r_l         = (const float*)d_in[8];
    const float* v_m         = (const float*)d_in[9];
    const float* u_m         = (const float*)d_in[10];
    const float* r_m         = (const float*)d_in[11];
    const float* noise_l     = (const float*)d_in[12];
    const float* noise_m     = (const float*)d_in[13];

    float*        out     = (float*)d_out;
    float*        partial = (float*)d_ws;                       // NBLK floats
    unsigned int* counter = (unsigned int*)((char*)d_ws + NBLK * sizeof(float));

    // counter must be 0 at the start of every call (ws is poisoned once, not re-poisoned)
    hipMemsetAsync(counter, 0, sizeof(unsigned int), stream);

    izh_all<<<NBLK, BLK, 0, stream>>>(
        reward, expected, aversion, da, goal, frustration,
        v_l, u_l, r_l, v_m, u_m, r_m,
        noise_l, noise_m, partial, counter, out);
}

// Round 4
// 170.857 us; speedup vs baseline: 1.7813x; 1.7813x over previous
//
#include <hip/hip_runtime.h>

// ---------------- constants from the reference ----------------
constexpr int   T       = 20;
constexpr int   N_LHB   = 2097152;
constexpr int   N_MHB   = 1048576;
constexpr float V_PEAK  = 30.0f;
constexpr float I_TONIC = -1.0f;
constexpr float THRESH  = 0.4f;
constexpr float DECAY   = 0.998f;
constexpr float GAIN    = 0.05f;

constexpr int BLK  = 256;
constexpr int VEC  = 8;                       // neurons per thread (2x float4 streams)
constexpr int NB_L = N_LHB / (VEC * BLK);     // 1024 blocks
constexpr int NB_M = N_MHB / (VEC * BLK);     // 512 blocks
constexpr int NBLK = NB_L + NB_M;             // 1536

// One Izhikevich step; returns spike as 0/1.
// c = drive + I_TONIC + 140 folded;  v1 = v*(0.04v+6) + (c + 0.5n - u)
__device__ __forceinline__ float istep(float& v, float& u, float n, float c) {
    float q  = fmaf(0.5f, n, c) - u;
    float p  = fmaf(0.04f, v, 6.0f);
    float v1 = fmaf(v, p, q);
    float u1 = fmaf(0.98f, u, 0.004f * v);   // u + 0.02*(0.2v - u)
    bool  s  = (v1 >= V_PEAK);
    v = s ? -65.0f : v1;
    u = s ? (u1 + 8.0f) : u1;
    return s ? 1.0f : 0.0f;
}

// Single fused kernel: Izhikevich run for both populations + last-block finalize.
// Prefetch pipeline uses NAMED buffers only (no arrays -> no scratch, R3 lesson).
__global__ __launch_bounds__(BLK) void izh_all(
    const float* __restrict__ reward, const float* __restrict__ expected,
    const float* __restrict__ aversion, const float* __restrict__ da,
    const int* __restrict__ goal, const float* __restrict__ frustration,
    const float* __restrict__ v_l, const float* __restrict__ u_l, const float* __restrict__ r_l,
    const float* __restrict__ v_m, const float* __restrict__ u_m, const float* __restrict__ r_m,
    const float* __restrict__ noise_l, const float* __restrict__ noise_m,
    float* __restrict__ partial, unsigned int* __restrict__ counter,
    float* __restrict__ out)
{
    const int bid = blockIdx.x;
    const int tid = threadIdx.x;

    const float4 *v4, *u4, *r4, *np;
    int n4, ia;
    float drive;
    if (bid < NB_L) {
        n4 = N_LHB / 4;
        ia = bid * (2 * BLK) + tid;
        v4 = (const float4*)v_l; u4 = (const float4*)u_l; r4 = (const float4*)r_l;
        np = (const float4*)noise_l;
        drive = fmaxf(0.0f, expected[0] - reward[0]) * 20.0f;   // disappoint*20
    } else {
        n4 = N_MHB / 4;
        ia = (bid - NB_L) * (2 * BLK) + tid;
        v4 = (const float4*)v_m; u4 = (const float4*)u_m; r4 = (const float4*)r_m;
        np = (const float4*)noise_m;
        drive = aversion[0] * 15.0f;
    }
    const int ib = ia + BLK;
    const float c = drive + I_TONIC + 140.0f;

    float4 va = v4[ia], vb = v4[ib];
    float4 ua = u4[ia], ub = u4[ib];
    float4 ra = r4[ia], rb = r4[ib];

    // per-thread running rate-sum via EMA linearity: S' = 0.9*S + 0.1*spikecount
    float S = (ra.x + ra.y) + (ra.z + ra.w) + (rb.x + rb.y) + (rb.z + rb.w);

    const float4* npp = np + ia;
    const float4* npq = np + ib;

    // depth-3 software pipeline, fully static (named buffers, macro-unrolled)
    float4 a0 = npp[0],              b0 = npq[0];
    float4 a1 = npp[(size_t)n4],     b1 = npq[(size_t)n4];
    float4 a2 = npp[(size_t)2 * n4], b2 = npq[(size_t)2 * n4];

#define DO_STEP(t, NA, NB)                                                     \
    {                                                                          \
        float cnt = istep(va.x, ua.x, NA.x, c) + istep(va.y, ua.y, NA.y, c)    \
                  + istep(va.z, ua.z, NA.z, c) + istep(va.w, ua.w, NA.w, c)    \
                  + istep(vb.x, ub.x, NB.x, c) + istep(vb.y, ub.y, NB.y, c)    \
                  + istep(vb.z, ub.z, NB.z, c) + istep(vb.w, ub.w, NB.w, c);   \
        S = fmaf(0.1f, cnt, 0.9f * S);                                         \
        if ((t) + 3 < T) {                                                     \
            NA = npp[(size_t)((t) + 3) * n4];                                  \
            NB = npq[(size_t)((t) + 3) * n4];                                  \
        }                                                                      \
    }

    DO_STEP(0,  a0, b0)  DO_STEP(1,  a1, b1)  DO_STEP(2,  a2, b2)
    DO_STEP(3,  a0, b0)  DO_STEP(4,  a1, b1)  DO_STEP(5,  a2, b2)
    DO_STEP(6,  a0, b0)  DO_STEP(7,  a1, b1)  DO_STEP(8,  a2, b2)
    DO_STEP(9,  a0, b0)  DO_STEP(10, a1, b1)  DO_STEP(11, a2, b2)
    DO_STEP(12, a0, b0)  DO_STEP(13, a1, b1)  DO_STEP(14, a2, b2)
    DO_STEP(15, a0, b0)  DO_STEP(16, a1, b1)  DO_STEP(17, a2, b2)
    DO_STEP(18, a0, b0)  DO_STEP(19, a1, b1)
#undef DO_STEP

    // deterministic block reduction
    #pragma unroll
    for (int o = 32; o > 0; o >>= 1) S += __shfl_down(S, o, 64);
    __shared__ float sh[4];
    if ((tid & 63) == 0) sh[tid >> 6] = S;
    __syncthreads();

    __shared__ unsigned int amLast;
    if (tid == 0) {
        float ps = (sh[0] + sh[1]) + (sh[2] + sh[3]);
        __hip_atomic_store(&partial[bid], ps, __ATOMIC_RELEASE, __HIP_MEMORY_SCOPE_AGENT);
        unsigned int old = __hip_atomic_fetch_add(counter, 1u, __ATOMIC_ACQ_REL,
                                                  __HIP_MEMORY_SCOPE_AGENT);
        // monotonic counter: exactly one block per call satisfies this,
        // regardless of the counter's starting value (works with 0xAA poison,
        // no memset needed, deterministic output).
        amLast = ((old + 1u) % (unsigned)NBLK == 0u) ? 1u : 0u;
    }
    __syncthreads();
    if (amLast == 0u) return;

    // ---------- last arriving block: final reduction + scalar bookkeeping ----------
    float sl = 0.0f, sm = 0.0f;
    for (int k = tid; k < NB_L; k += BLK)
        sl += __hip_atomic_load(&partial[k], __ATOMIC_RELAXED, __HIP_MEMORY_SCOPE_AGENT);
    for (int k = tid; k < NB_M; k += BLK)
        sm += __hip_atomic_load(&partial[NB_L + k], __ATOMIC_RELAXED, __HIP_MEMORY_SCOPE_AGENT);
    #pragma unroll
    for (int o = 32; o > 0; o >>= 1) {
        sl += __shfl_down(sl, o, 64);
        sm += __shfl_down(sm, o, 64);
    }
    __shared__ float sh2[8];
    if ((tid & 63) == 0) { sh2[tid >> 6] = sl; sh2[4 + (tid >> 6)] = sm; }
    __syncthreads();

    if (tid == 0) {
        float lhb_mean = ((sh2[0] + sh2[1]) + (sh2[2] + sh2[3])) / (float)N_LHB;
        float mhb_mean = ((sh2[4] + sh2[5]) + (sh2[6] + sh2[7])) / (float)N_MHB;

        float rpe = reward[0] - expected[0];
        float disappoint = fmaxf(0.0f, -rpe);
        float da_supp = fminf(0.5f, lhb_mean * 5.0f);
        float ht5_supp = fminf(0.3f, lhb_mean * 3.0f);

        int g = goal[0];
        float f[4];
        #pragma unroll
        for (int k = 0; k < 4; ++k) f[k] = frustration[k] * DECAY;
        f[g] += (rpe < -0.05f) ? GAIN * fabsf(rpe) : 0.0f;
        f[g] *= (rpe > 0.1f) ? 0.8f : 1.0f;
        #pragma unroll
        for (int k = 0; k < 4; ++k) f[k] = fminf(1.0f, fmaxf(0.0f, f[k]));
        float helplessness = fmaxf(fmaxf(f[0], f[1]), fmaxf(f[2], f[3]));
        float sw = (f[g] > THRESH) ? 1.0f : 0.0f;
        f[g] *= (sw > 0.0f) ? 0.3f : 1.0f;

        float dopa_mod = fmaxf(0.5f, 2.0f * (1.0f - da[0]));
        float explore = fminf(1.0f, disappoint * 2.0f + lhb_mean * 3.0f);

        out[0] = disappoint;
        out[1] = da_supp;
        out[2] = ht5_supp;
        out[3] = lhb_mean;
        out[4] = mhb_mean;
        out[5] = explore;
        out[6] = helplessness;
        out[7] = sw;
        #pragma unroll
        for (int k = 0; k < 4; ++k) out[8 + k]  = f[k] * 0.5f * dopa_mod;
        #pragma unroll
        for (int k = 0; k < 4; ++k) out[12 + k] = f[k];
    }
}

extern "C" void kernel_launch(void* const* d_in, const int* in_sizes, int n_in,
                              void* d_out, int out_size, void* d_ws, size_t ws_size,
                              hipStream_t stream) {
    const float* reward      = (const float*)d_in[0];
    const float* expected    = (const float*)d_in[1];
    const float* aversion    = (const float*)d_in[2];
    const float* da          = (const float*)d_in[3];
    const int*   goal        = (const int*)d_in[4];
    const float* frustration = (const float*)d_in[5];
    const float* v_l         = (const float*)d_in[6];
    const float* u_l         = (const float*)d_in[7];
    const float* r_l         = (const float*)d_in[8];
    const float* v_m         = (const float*)d_in[9];
    const float* u_m         = (const float*)d_in[10];
    const float* r_m         = (const float*)d_in[11];
    const float* noise_l     = (const float*)d_in[12];
    const float* noise_m     = (const float*)d_in[13];

    float*        out     = (float*)d_out;
    float*        partial = (float*)d_ws;                        // NBLK floats
    unsigned int* counter = (unsigned int*)((char*)d_ws + NBLK * sizeof(float));

    izh_all<<<NBLK, BLK, 0, stream>>>(
        reward, expected, aversion, da, goal, frustration,
        v_l, u_l, r_l, v_m, u_m, r_m,
        noise_l, noise_m, partial, counter, out);
}

// Round 5
// 115.281 us; speedup vs baseline: 2.6400x; 1.4821x over previous
//
#include <hip/hip_runtime.h>

// ---------------- constants from the reference ----------------
constexpr int   T       = 20;
constexpr int   N_LHB   = 2097152;
constexpr int   N_MHB   = 1048576;
constexpr float V_PEAK  = 30.0f;
constexpr float I_TONIC = -1.0f;
constexpr float THRESH  = 0.4f;
constexpr float DECAY   = 0.998f;
constexpr float GAIN    = 0.05f;

constexpr int BLK  = 256;
constexpr int VEC  = 8;                       // neurons per thread (2x float4 streams)
constexpr int NB_L = N_LHB / (VEC * BLK);     // 1024 blocks
constexpr int NB_M = N_MHB / (VEC * BLK);     // 512 blocks
constexpr int NBLK = NB_L + NB_M;             // 1536 producer blocks (+1 waiter)
constexpr int PF   = 3;                       // noise prefetch depth (steps)

// One Izhikevich step for one neuron; returns spike as 0/1 float.
// c = drive + I_TONIC + 140 folded;  v1 = v*(0.04v+6) + (c + 0.5n - u)
__device__ __forceinline__ float istep(float& v, float& u, float n, float c) {
    float q  = fmaf(0.5f, n, c) - u;
    float p  = fmaf(0.04f, v, 6.0f);
    float v1 = fmaf(v, p, q);
    float u1 = fmaf(0.98f, u, 0.004f * v);   // u + 0.02*(0.2v - u)
    bool  s  = (v1 >= V_PEAK);
    v = s ? -65.0f : v1;
    u = s ? (u1 + 8.0f) : u1;
    return s ? 1.0f : 0.0f;
}

// Single launch: blocks 0..NBLK-1 run the Izhikevich populations (R2's exact
// loop), block NBLK is a dedicated waiter that spins on an exact-count counter
// (memset to 0 each call) and then does the final reduction + scalar logic.
// All 1537 blocks fit residency (<= 8 blocks/CU * 256 CU), so the waiter can
// never starve the producers.
__global__ __launch_bounds__(BLK) void izh_all(
    const float* __restrict__ reward, const float* __restrict__ expected,
    const float* __restrict__ aversion, const float* __restrict__ da,
    const int* __restrict__ goal, const float* __restrict__ frustration,
    const float* __restrict__ v_l, const float* __restrict__ u_l, const float* __restrict__ r_l,
    const float* __restrict__ v_m, const float* __restrict__ u_m, const float* __restrict__ r_m,
    const float* __restrict__ noise_l, const float* __restrict__ noise_m,
    float* __restrict__ partial, unsigned int* __restrict__ counter,
    float* __restrict__ out)
{
    const int bid = blockIdx.x;
    const int tid = threadIdx.x;

    if (bid >= NBLK) {
        // ---------------- waiter block: finalize ----------------
        if (tid == 0) {
            while (__hip_atomic_load(counter, __ATOMIC_ACQUIRE,
                                     __HIP_MEMORY_SCOPE_AGENT) != (unsigned)NBLK)
                __builtin_amdgcn_s_sleep(2);
        }
        __syncthreads();

        float sl = 0.0f, sm = 0.0f;
        for (int k = tid; k < NB_L; k += BLK)
            sl += __hip_atomic_load(&partial[k], __ATOMIC_RELAXED, __HIP_MEMORY_SCOPE_AGENT);
        for (int k = tid; k < NB_M; k += BLK)
            sm += __hip_atomic_load(&partial[NB_L + k], __ATOMIC_RELAXED, __HIP_MEMORY_SCOPE_AGENT);
        #pragma unroll
        for (int o = 32; o > 0; o >>= 1) {
            sl += __shfl_down(sl, o, 64);
            sm += __shfl_down(sm, o, 64);
        }
        __shared__ float sh2[8];
        if ((tid & 63) == 0) { sh2[tid >> 6] = sl; sh2[4 + (tid >> 6)] = sm; }
        __syncthreads();

        if (tid == 0) {
            float lhb_mean = ((sh2[0] + sh2[1]) + (sh2[2] + sh2[3])) / (float)N_LHB;
            float mhb_mean = ((sh2[4] + sh2[5]) + (sh2[6] + sh2[7])) / (float)N_MHB;

            float rpe = reward[0] - expected[0];
            float disappoint = fmaxf(0.0f, -rpe);
            float da_supp = fminf(0.5f, lhb_mean * 5.0f);
            float ht5_supp = fminf(0.3f, lhb_mean * 3.0f);

            int g = goal[0];
            float f[4];
            #pragma unroll
            for (int k = 0; k < 4; ++k) f[k] = frustration[k] * DECAY;
            f[g] += (rpe < -0.05f) ? GAIN * fabsf(rpe) : 0.0f;
            f[g] *= (rpe > 0.1f) ? 0.8f : 1.0f;
            #pragma unroll
            for (int k = 0; k < 4; ++k) f[k] = fminf(1.0f, fmaxf(0.0f, f[k]));
            float helplessness = fmaxf(fmaxf(f[0], f[1]), fmaxf(f[2], f[3]));
            float sw = (f[g] > THRESH) ? 1.0f : 0.0f;
            f[g] *= (sw > 0.0f) ? 0.3f : 1.0f;

            float dopa_mod = fmaxf(0.5f, 2.0f * (1.0f - da[0]));
            float explore = fminf(1.0f, disappoint * 2.0f + lhb_mean * 3.0f);

            out[0] = disappoint;
            out[1] = da_supp;
            out[2] = ht5_supp;
            out[3] = lhb_mean;
            out[4] = mhb_mean;
            out[5] = explore;
            out[6] = helplessness;
            out[7] = sw;
            #pragma unroll
            for (int k = 0; k < 4; ++k) out[8 + k]  = f[k] * 0.5f * dopa_mod;
            #pragma unroll
            for (int k = 0; k < 4; ++k) out[12 + k] = f[k];
        }
        return;
    }

    // ---------------- producer blocks: R2's exact main loop ----------------
    const float4 *v4, *u4, *r4, *np;
    int n4, ia;
    float drive;
    if (bid < NB_L) {
        n4 = N_LHB / 4;
        ia = bid * (2 * BLK) + tid;
        v4 = (const float4*)v_l; u4 = (const float4*)u_l; r4 = (const float4*)r_l;
        np = (const float4*)noise_l;
        drive = fmaxf(0.0f, expected[0] - reward[0]) * 20.0f;   // disappoint*20
    } else {
        n4 = N_MHB / 4;
        ia = (bid - NB_L) * (2 * BLK) + tid;
        v4 = (const float4*)v_m; u4 = (const float4*)u_m; r4 = (const float4*)r_m;
        np = (const float4*)noise_m;
        drive = aversion[0] * 15.0f;
    }
    const int ib = ia + BLK;
    const float c = drive + I_TONIC + 140.0f;

    float4 va = v4[ia], vb = v4[ib];
    float4 ua = u4[ia], ub = u4[ib];
    float4 ra = r4[ia], rb = r4[ib];

    // per-thread running rate-sum via EMA linearity: S' = 0.9*S + 0.1*spikecount
    float S = (ra.x + ra.y) + (ra.z + ra.w) + (rb.x + rb.y) + (rb.z + rb.w);

    // depth-PF software pipeline on the noise stream
    float4 na[PF], nb[PF];
    #pragma unroll
    for (int t = 0; t < PF; ++t) {
        na[t] = (np + ia)[(size_t)t * n4];
        nb[t] = (np + ib)[(size_t)t * n4];
    }

    #pragma unroll
    for (int t = 0; t < T; ++t) {
        const float4 cna = na[t % PF];
        const float4 cnb = nb[t % PF];
        if (t + PF < T) {
            na[t % PF] = (np + ia)[(size_t)(t + PF) * n4];
            nb[t % PF] = (np + ib)[(size_t)(t + PF) * n4];
        }
        float cnt = istep(va.x, ua.x, cna.x, c) + istep(va.y, ua.y, cna.y, c)
                  + istep(va.z, ua.z, cna.z, c) + istep(va.w, ua.w, cna.w, c)
                  + istep(vb.x, ub.x, cnb.x, c) + istep(vb.y, ub.y, cnb.y, c)
                  + istep(vb.z, ub.z, cnb.z, c) + istep(vb.w, ub.w, cnb.w, c);
        S = fmaf(0.1f, cnt, 0.9f * S);
    }

    // deterministic block reduction
    #pragma unroll
    for (int o = 32; o > 0; o >>= 1) S += __shfl_down(S, o, 64);
    __shared__ float sh[4];
    if ((tid & 63) == 0) sh[tid >> 6] = S;
    __syncthreads();

    if (tid == 0) {
        partial[bid] = (sh[0] + sh[1]) + (sh[2] + sh[3]);
        // release: publishes the partial store before the count is visible
        __hip_atomic_fetch_add(counter, 1u, __ATOMIC_RELEASE, __HIP_MEMORY_SCOPE_AGENT);
    }
}

extern "C" void kernel_launch(void* const* d_in, const int* in_sizes, int n_in,
                              void* d_out, int out_size, void* d_ws, size_t ws_size,
                              hipStream_t stream) {
    const float* reward      = (const float*)d_in[0];
    const float* expected    = (const float*)d_in[1];
    const float* aversion    = (const float*)d_in[2];
    const float* da          = (const float*)d_in[3];
    const int*   goal        = (const int*)d_in[4];
    const float* frustration = (const float*)d_in[5];
    const float* v_l         = (const float*)d_in[6];
    const float* u_l         = (const float*)d_in[7];
    const float* r_l         = (const float*)d_in[8];
    const float* v_m         = (const float*)d_in[9];
    const float* u_m         = (const float*)d_in[10];
    const float* r_m         = (const float*)d_in[11];
    const float* noise_l     = (const float*)d_in[12];
    const float* noise_m     = (const float*)d_in[13];

    float*        out     = (float*)d_out;
    float*        partial = (float*)d_ws;                        // NBLK floats
    unsigned int* counter = (unsigned int*)((char*)d_ws + NBLK * sizeof(float));

    // exact-count sync: counter must start at 0 every call
    hipMemsetAsync(counter, 0, sizeof(unsigned int), stream);

    izh_all<<<NBLK + 1, BLK, 0, stream>>>(
        reward, expected, aversion, da, goal, frustration,
        v_l, u_l, r_l, v_m, u_m, r_m,
        noise_l, noise_m, partial, counter, out);
}

// Round 6
// 53.498 us; speedup vs baseline: 5.6889x; 2.1549x over previous
//
#include <hip/hip_runtime.h>

// ---------------- constants from the reference ----------------
constexpr int   T       = 20;
constexpr int   N_LHB   = 2097152;
constexpr int   N_MHB   = 1048576;
constexpr float V_PEAK  = 30.0f;
constexpr float I_TONIC = -1.0f;
constexpr float THRESH  = 0.4f;
constexpr float DECAY   = 0.998f;
constexpr float GAIN    = 0.05f;

constexpr int BLK  = 256;
constexpr int VEC  = 8;                       // neurons per thread (2x float4)
constexpr int NB_L = N_LHB / (VEC * BLK);     // 1024 blocks
constexpr int NB_M = N_MHB / (VEC * BLK);     // 512 blocks
constexpr int PF   = 4;                       // noise prefetch depth (steps)

// One Izhikevich step for one neuron; returns spike as 0/1 float.
// c = drive + I_TONIC + 140 folded;  v1 = v*(0.04v+6) + (c + 0.5n - u)
__device__ __forceinline__ float istep(float& v, float& u, float n, float c) {
    float q  = fmaf(0.5f, n, c) - u;
    float p  = fmaf(0.04f, v, 6.0f);
    float v1 = fmaf(v, p, q);
    float u1 = fmaf(0.98f, u, 0.004f * v);   // u + 0.02*(0.2v - u)
    bool  s  = (v1 >= V_PEAK);
    v = s ? -65.0f : v1;
    u = s ? (u1 + 8.0f) : u1;
    return s ? 1.0f : 0.0f;
}

// Fused LHB+MHB run. Each thread owns 8 neurons (two float4 streams).
// Per-thread rate-sum uses the EMA's linearity: S' = 0.9*S + 0.1*spikecount.
__global__ __launch_bounds__(BLK) void izh_fused(
    const float* __restrict__ reward, const float* __restrict__ expected,
    const float* __restrict__ aversion,
    const float* __restrict__ v_l, const float* __restrict__ u_l, const float* __restrict__ r_l,
    const float* __restrict__ v_m, const float* __restrict__ u_m, const float* __restrict__ r_m,
    const float* __restrict__ noise_l, const float* __restrict__ noise_m,
    float* __restrict__ partial)
{
    const int bid = blockIdx.x;
    const int tid = threadIdx.x;

    const float4 *v4, *u4, *r4, *np;
    int n4, ia;
    float drive;
    if (bid < NB_L) {
        n4 = N_LHB / 4;
        ia = bid * (2 * BLK) + tid;
        v4 = (const float4*)v_l; u4 = (const float4*)u_l; r4 = (const float4*)r_l;
        np = (const float4*)noise_l;
        drive = fmaxf(0.0f, expected[0] - reward[0]) * 20.0f;   // disappoint*20
    } else {
        n4 = N_MHB / 4;
        ia = (bid - NB_L) * (2 * BLK) + tid;
        v4 = (const float4*)v_m; u4 = (const float4*)u_m; r4 = (const float4*)r_m;
        np = (const float4*)noise_m;
        drive = aversion[0] * 15.0f;
    }
    const int ib = ia + BLK;
    const float c = drive + I_TONIC + 140.0f;

    float4 va = v4[ia], vb = v4[ib];
    float4 ua = u4[ia], ub = u4[ib];
    float4 ra = r4[ia], rb = r4[ib];

    // per-thread running rate-sum (sum over the 8 owned neurons)
    float S = (ra.x + ra.y) + (ra.z + ra.w) + (rb.x + rb.y) + (rb.z + rb.w);

    // depth-PF software pipeline on the noise stream
    float4 na[PF], nb[PF];
    #pragma unroll
    for (int t = 0; t < PF; ++t) {
        na[t] = np[(size_t)t * n4 + ia];
        nb[t] = np[(size_t)t * n4 + ib];
    }

    #pragma unroll
    for (int t = 0; t < T; ++t) {
        const float4 cna = na[t % PF];
        const float4 cnb = nb[t % PF];
        if (t + PF < T) {
            na[t % PF] = np[(size_t)(t + PF) * n4 + ia];
            nb[t % PF] = np[(size_t)(t + PF) * n4 + ib];
        }
        float cnt = istep(va.x, ua.x, cna.x, c) + istep(va.y, ua.y, cna.y, c)
                  + istep(va.z, ua.z, cna.z, c) + istep(va.w, ua.w, cna.w, c)
                  + istep(vb.x, ub.x, cnb.x, c) + istep(vb.y, ub.y, cnb.y, c)
                  + istep(vb.z, ub.z, cnb.z, c) + istep(vb.w, ub.w, cnb.w, c);
        S = fmaf(0.1f, cnt, 0.9f * S);
    }

    // block reduction (deterministic tree)
    #pragma unroll
    for (int o = 32; o > 0; o >>= 1) S += __shfl_down(S, o, 64);

    __shared__ float sh[4];
    if ((tid & 63) == 0) sh[tid >> 6] = S;
    __syncthreads();
    if (tid == 0) partial[bid] = (sh[0] + sh[1]) + (sh[2] + sh[3]);
}

// Single-block reduction of partials + all scalar bookkeeping -> 16 outputs.
__global__ __launch_bounds__(BLK) void finalize(
    const float* __restrict__ partial,
    const float* __restrict__ reward, const float* __restrict__ expected,
    const float* __restrict__ aversion, const float* __restrict__ da,
    const int* __restrict__ goal, const float* __restrict__ frustration,
    float* __restrict__ out)
{
    const int tid = threadIdx.x;
    float sl = 0.0f, sm = 0.0f;
    for (int i = tid; i < NB_L; i += BLK) sl += partial[i];
    for (int i = tid; i < NB_M; i += BLK) sm += partial[NB_L + i];
    #pragma unroll
    for (int o = 32; o > 0; o >>= 1) {
        sl += __shfl_down(sl, o, 64);
        sm += __shfl_down(sm, o, 64);
    }
    __shared__ float sh[8];
    if ((tid & 63) == 0) { sh[tid >> 6] = sl; sh[4 + (tid >> 6)] = sm; }
    __syncthreads();

    if (tid == 0) {
        float lhb_mean = ((sh[0] + sh[1]) + (sh[2] + sh[3])) / (float)N_LHB;
        float mhb_mean = ((sh[4] + sh[5]) + (sh[6] + sh[7])) / (float)N_MHB;

        float rpe = reward[0] - expected[0];
        float disappoint = fmaxf(0.0f, -rpe);
        float da_supp = fminf(0.5f, lhb_mean * 5.0f);
        float ht5_supp = fminf(0.3f, lhb_mean * 3.0f);

        int g = goal[0];
        float f[4];
        #pragma unroll
        for (int k = 0; k < 4; ++k) f[k] = frustration[k] * DECAY;
        f[g] += (rpe < -0.05f) ? GAIN * fabsf(rpe) : 0.0f;
        f[g] *= (rpe > 0.1f) ? 0.8f : 1.0f;
        #pragma unroll
        for (int k = 0; k < 4; ++k) f[k] = fminf(1.0f, fmaxf(0.0f, f[k]));
        float helplessness = fmaxf(fmaxf(f[0], f[1]), fmaxf(f[2], f[3]));
        float sw = (f[g] > THRESH) ? 1.0f : 0.0f;
        f[g] *= (sw > 0.0f) ? 0.3f : 1.0f;

        float dopa_mod = fmaxf(0.5f, 2.0f * (1.0f - da[0]));
        float explore = fminf(1.0f, disappoint * 2.0f + lhb_mean * 3.0f);

        out[0] = disappoint;
        out[1] = da_supp;
        out[2] = ht5_supp;
        out[3] = lhb_mean;
        out[4] = mhb_mean;
        out[5] = explore;
        out[6] = helplessness;
        out[7] = sw;
        #pragma unroll
        for (int k = 0; k < 4; ++k) out[8 + k] = f[k] * 0.5f * dopa_mod;
        #pragma unroll
        for (int k = 0; k < 4; ++k) out[12 + k] = f[k];
    }
}

extern "C" void kernel_launch(void* const* d_in, const int* in_sizes, int n_in,
                              void* d_out, int out_size, void* d_ws, size_t ws_size,
                              hipStream_t stream) {
    const float* reward      = (const float*)d_in[0];
    const float* expected    = (const float*)d_in[1];
    const float* aversion    = (const float*)d_in[2];
    const float* da          = (const float*)d_in[3];
    const int*   goal        = (const int*)d_in[4];
    const float* frustration = (const float*)d_in[5];
    const float* v_l         = (const float*)d_in[6];
    const float* u_l         = (const float*)d_in[7];
    const float* r_l         = (const float*)d_in[8];
    const float* v_m         = (const float*)d_in[9];
    const float* u_m         = (const float*)d_in[10];
    const float* r_m         = (const float*)d_in[11];
    const float* noise_l     = (const float*)d_in[12];
    const float* noise_m     = (const float*)d_in[13];

    float* out     = (float*)d_out;
    float* partial = (float*)d_ws;   // NB_L + NB_M = 1536 floats = 6 KiB

    izh_fused<<<NB_L + NB_M, BLK, 0, stream>>>(
        reward, expected, aversion,
        v_l, u_l, r_l, v_m, u_m, r_m,
        noise_l, noise_m, partial);

    finalize<<<1, BLK, 0, stream>>>(
        partial, reward, expected, aversion, da, goal, frustration, out);
}